// Round 13
// baseline (166.674 us; speedup 1.0000x reference)
//
#include <hip/hip_runtime.h>

// ComplexMultiheadAttention, MI355X/gfx950.
// Pipeline: cvt(f32->bf16) -> proj GEMMs (qr,qi,kr,ki,vr^T) -> banded flash attn -> out proj.
// B=2, L=4096, E=512, H=8, D=64, W=128 (mask: j <= i-129 is -inf; NO causal/upper mask).
// Softmax in log2 domain (0.125*log2(e) folded into q proj), NO max tracking (scores O(1);
// constant max cancels in O/l; masked -3e38 underflows to 0).
// exp2 via RAW v_exp_f32 (not exp2f -> OCML precise-path bloat: ~10-15 VALU insts/call).
// Attn: QB=64, 4 waves = 2 q-waves x 2 k-groups; KB=32. 1024 blocks (heavy-first),
// 48KB LDS ping-pong -> 3 blocks/CU + backfill. Exact in-LDS merge: O=O0+O1, l=l0+l1.

typedef unsigned short u16;
typedef unsigned int u32;
typedef __attribute__((ext_vector_type(8))) short bf16x8;
typedef __attribute__((ext_vector_type(4))) float f32x4;
typedef __attribute__((ext_vector_type(16))) float f32x16;
typedef __attribute__((ext_vector_type(4))) u32 u32x4;

#define L_ 4096
#define E_ 512
#define M_ 8192  // B*L

__device__ __forceinline__ u16 f2bf(float f) {
  union { float f; u32 u; } v; v.f = f;
  return (u16)((v.u + 0x7FFFu + ((v.u >> 16) & 1u)) >> 16);  // RNE
}

__device__ __forceinline__ float fexp2(float x) {
  float r;
  asm("v_exp_f32 %0, %1" : "=v"(r) : "v"(x));  // HW 2^x: 1-ulp, underflows to 0
  return r;
}

__device__ __forceinline__ void gll16(const void* g, void* l) {
  __builtin_amdgcn_global_load_lds(
      (const __attribute__((address_space(1))) u32*)g,
      (__attribute__((address_space(3))) u32*)l, 16, 0, 0);
}

// ---------------- conversion kernels ----------------
__global__ void cvt_x_kernel(const float* __restrict__ q, const float* __restrict__ k,
                             const float* __restrict__ v,
                             u16* __restrict__ xq, u16* __restrict__ xk, u16* __restrict__ xv) {
  const int total = 3 * (M_ * E_ / 4);  // float4 units, 1<<20 per matrix
  int stride = gridDim.x * blockDim.x;
  for (int u = blockIdx.x * blockDim.x + threadIdx.x; u < total; u += stride) {
    int mat = u >> 20, e = u & ((1 << 20) - 1);
    const float4 f = ((const float4*)(mat == 0 ? q : mat == 1 ? k : v))[e];
    ushort4 o = make_ushort4(f2bf(f.x), f2bf(f.y), f2bf(f.z), f2bf(f.w));
    *(ushort4*)((mat == 0 ? xq : mat == 1 ? xk : xv) + (size_t)e * 4) = o;
  }
}

struct CPtrs { const float* w[7]; const float* b[7]; };

__global__ void cvt_wb_kernel(CPtrs p, u16* __restrict__ wcat, float* __restrict__ bcat) {
  // wcat rows: [qWr|qWi|kWr|kWi|vWr|oWr|oWi], each 512x512. bcat matching biases.
  const int total = 7 * (E_ * E_ / 4);  // 65536 float4 per matrix
  int stride = gridDim.x * blockDim.x;
  int t0 = blockIdx.x * blockDim.x + threadIdx.x;
  for (int u = t0; u < total; u += stride) {
    int wi = u >> 16, e = u & 65535;
    const float4 f = ((const float4*)p.w[wi])[e];
    ushort4 o = make_ushort4(f2bf(f.x), f2bf(f.y), f2bf(f.z), f2bf(f.w));
    *(ushort4*)(wcat + (size_t)wi * 262144 + (size_t)e * 4) = o;
  }
  for (int j = t0; j < 3584; j += stride) bcat[j] = p.b[j >> 9][j & 511];
}

// ---------------- 128x128 bf16 GEMM mainloop (C = A @ W^T), K=512, BK=32 ----------------
__device__ __forceinline__ void gemm128_main(const u16* __restrict__ A, const u16* __restrict__ Bw,
                                             int m0, int n0w, char* sm, f32x4 acc[4][4]) {
  int tid = threadIdx.x;
  int lane = tid & 63, w = tid >> 6;
  int wm = w >> 1, wn = w & 1;
#pragma unroll
  for (int a = 0; a < 4; a++)
#pragma unroll
    for (int b = 0; b < 4; b++)
#pragma unroll
      for (int j = 0; j < 4; j++) acc[a][b][j] = 0.f;

  auto stage = [&](int buf, int ks) {
    char* dst = sm + buf * 16384;
#pragma unroll
    for (int n = 0; n < 2; n++) {
      int u = n * 256 + tid;
      int row = u >> 2, c = u & 3;
      int so = (c ^ (row & 3)) * 16;  // pre-swizzled source chunk (LDS stays linear)
      int ldso = (n * 256 + w * 64) * 16;
      gll16((const char*)(A + (size_t)(m0 + row) * 512 + ks * 32) + so, dst + ldso);
      gll16((const char*)(Bw + (size_t)(n0w + row) * 512 + ks * 32) + so, dst + 8192 + ldso);
    }
  };

  stage(0, 0);
  __syncthreads();
  int cur = 0;
  for (int ks = 0; ks < 16; ks++) {
    if (ks < 15) stage(cur ^ 1, ks + 1);
    const char* as = sm + cur * 16384;
    const char* bs = as + 8192;
    bf16x8 af[4], bfr[4];
#pragma unroll
    for (int i = 0; i < 4; i++) {
      int ra = wm * 64 + i * 16 + (lane & 15);
      af[i] = *(const bf16x8*)(as + ra * 64 + (((lane >> 4) * 16) ^ ((ra & 3) << 4)));
      int rb = wn * 64 + i * 16 + (lane & 15);
      bfr[i] = *(const bf16x8*)(bs + rb * 64 + (((lane >> 4) * 16) ^ ((rb & 3) << 4)));
    }
    __builtin_amdgcn_s_setprio(1);
#pragma unroll
    for (int mt = 0; mt < 4; mt++)
#pragma unroll
      for (int nt = 0; nt < 4; nt++)
        acc[mt][nt] = __builtin_amdgcn_mfma_f32_16x16x32_bf16(af[mt], bfr[nt], acc[mt][nt], 0, 0, 0);
    __builtin_amdgcn_s_setprio(0);
    __syncthreads();
    cur ^= 1;
  }
}

// ---------------- projection kernel (q,k,v jobs) ----------------
__global__ __launch_bounds__(256) void proj_kernel(
    const u16* __restrict__ xq, const u16* __restrict__ xk, const u16* __restrict__ xv,
    const u16* __restrict__ wcat, const float* __restrict__ bcat,
    u16* __restrict__ qrb, u16* __restrict__ qib,
    u16* __restrict__ krb, u16* __restrict__ kib, u16* __restrict__ vtb) {
  __shared__ alignas(16) char sm[32768];
  int bx = blockIdx.x, by = blockIdx.y;  // bx<8: q (N=1024), bx<16: k, else v (N=512)
  const u16* A = bx < 8 ? xq : (bx < 16 ? xk : xv);
  int m0 = by * 128, n0w = bx * 128;
  f32x4 acc[4][4];
  gemm128_main(A, wcat, m0, n0w, sm, acc);

  int lane = threadIdx.x & 63, w = threadIdx.x >> 6;
  int wm = w >> 1, wn = w & 1;
  int lL = lane & 15, lH = lane >> 4;
#pragma unroll
  for (int mt = 0; mt < 4; mt++) {
#pragma unroll
    for (int nt = 0; nt < 4; nt++) {
      int n = n0w + wn * 64 + nt * 16 + lL;  // global wcat row
      float bias = bcat[n];
      int e = n & 511;
#pragma unroll
      for (int j = 0; j < 4; j++) {
        int m = m0 + wm * 64 + mt * 16 + lH * 4 + j;
        float val = acc[mt][nt][j] + bias;
        int bb = m >> 12, ll = m & 4095;
        if (bx < 16) {
          if (bx < 8) val *= 0.18033688011112042f;  // 1/sqrt(D) * log2(e) folded into q
          u16* dst = (bx < 8) ? ((n & 512) ? qib : qrb) : ((n & 512) ? kib : krb);
          dst[((size_t)((bb * 8 + (e >> 6)) * 4096 + ll) << 6) + (e & 63)] = f2bf(val);
        } else {
          // vr stored transposed: VT[bh][d][l]
          vtb[((size_t)((bb * 8 + (e >> 6)) * 64 + (e & 63)) << 12) + ll] = f2bf(val);
        }
      }
    }
  }
}

// ---------------- output projection kernel ----------------
__global__ __launch_bounds__(256) void oproj_kernel(
    const u16* __restrict__ obf, const u16* __restrict__ wcat, const float* __restrict__ bcat,
    float* __restrict__ out) {
  __shared__ alignas(16) char sm[32768];
  int bx = blockIdx.x, by = blockIdx.y;
  int m0 = by * 128, n0w = 2560 + bx * 128;
  f32x4 acc[4][4];
  gemm128_main(obf, wcat, m0, n0w, sm, acc);

  int lane = threadIdx.x & 63, w = threadIdx.x >> 6;
  int wm = w >> 1, wn = w & 1;
  int lL = lane & 15, lH = lane >> 4;
#pragma unroll
  for (int mt = 0; mt < 4; mt++) {
#pragma unroll
    for (int nt = 0; nt < 4; nt++) {
      int n = n0w + wn * 64 + nt * 16 + lL;
      float bias = bcat[n];
      int nn = n - 2560;
      // out_r at [0, 4194304), out_i at [4194304, 8388608)  (B*L*E = 4194304 each)
      float* dst = out + ((nn & 512) ? 4194304 : 0) + (nn & 511);
#pragma unroll
      for (int j = 0; j < 4; j++) {
        int m = m0 + wm * 64 + mt * 16 + lH * 4 + j;
        dst[(size_t)m * 512] = acc[mt][nt][j] + bias;
      }
    }
  }
}

// ---------------- banded flash attention (QB=64, 4 waves, 2 k-groups, backfilled) -----
// Waves: wq = w&1 (q-wave, 32 rows each), grp = w>>1 (k-group, tiles t%2==grp, KB=32).
// Swapped QK^T: S^T = mfma(K, Q); layout col=lane&31 (=q), row=(r&3)+8*(r>>2)+4*hi (=k).
// LDS: 2 x 24KB ping-pong halves. Half layout: KrA@0 KiA@4K KrB@8K KiB@12K (each 32x128B,
// XOR-swizzled rows) | VT@16K = [64d][64k] rows of 128B (both tiles' k), same swizzle.
// 24 chunks x 1KB (8 rows x 128B); thread stages 6 chunks/period via gll16.
__global__ __launch_bounds__(256, 3) void attn_kernel(
    const u16* __restrict__ qrb, const u16* __restrict__ qib,
    const u16* __restrict__ krb, const u16* __restrict__ kib,
    const u16* __restrict__ vtb, u16* __restrict__ obf) {
  __shared__ alignas(16) char sm[49152];  // 2 x 24KB; epilogue reuses ~17KB
  int bid = blockIdx.x;
  int bh = bid & 15;          // bh pins to XCD (bid%8==bh%8)
  int qt = bid >> 4;          // 0..63, ascending = heavy-first (backfill-friendly)
  int bb = bh >> 3, hh = bh & 7;
  int i0 = qt << 6;
  int tid = threadIdx.x;
  int lane = tid & 63, w = tid >> 6;    // w 0..3
  int grp = w >> 1, wq = w & 1;
  int lo = lane & 31, hi = lane >> 5;
  int i0w = i0 + wq * 32;
  int irow = i0w + lo;

  int jstart = (i0 >= 128) ? (i0 - 128) : 0;
  int ntiles = (4096 - jstart) >> 5;  // KB=32; always even
  int nper = ntiles >> 1;

  // ---- Q fragments (B-operand): lane holds Q[q=lo][d = c*16 + hi*8 + i] ----
  bf16x8 fqr[4], fqi[4];
  {
    const u16* qp = qrb + ((size_t)(bh * 4096 + irow) << 6) + hi * 8;
    const u16* qip = qib + ((size_t)(bh * 4096 + irow) << 6) + hi * 8;
#pragma unroll
    for (int c = 0; c < 4; c++) {
      fqr[c] = *(const bf16x8*)(qp + c * 16);
      fqi[c] = *(const bf16x8*)(qip + c * 16);
    }
  }

  // ---- per-thread staging constants: 6 chunks (1KB = 8 rows x 128B) per period ----
  // cc = 6w+s: 0-3 KrA, 4-7 KiA, 8-11 KrB, 12-15 KiB, 16-23 VT[64d][64k-per-period].
  const char* gp[6];
  int adv[6], ldso[6];
  {
    const char* krbB = (const char*)krb + ((size_t)(bh * 4096 + jstart) << 7);
    const char* kibB = (const char*)kib + ((size_t)(bh * 4096 + jstart) << 7);
    const char* vtbB = (const char*)vtb + ((size_t)(bh * 64) << 13) + ((size_t)jstart << 1);
#pragma unroll
    for (int s = 0; s < 6; s++) {
      int cc = 6 * w + s;
      ldso[s] = cc << 10;
      if (cc < 16) {  // K chunks: tile tI=cc>>3, kind=(cc>>2)&1 (Kr/Ki), rows 32 x 128B
        int tI = cc >> 3;
        int kind = (cc >> 2) & 1;
        int r = (cc & 3) * 8 + (lane >> 3);
        int so = ((lane & 7) ^ (r & 7)) << 4;
        gp[s] = (kind ? kibB : krbB) + (size_t)(tI * 32 + r) * 128 + so;
        adv[s] = 8192;  // 64 k-rows per period
      } else {        // VT chunks: rows d, 128B = 64 k (both tiles)
        int dr = (cc - 16) * 8 + (lane >> 3);
        int so = ((lane & 7) ^ (dr & 7)) << 4;
        gp[s] = vtbB + (size_t)dr * 8192 + so;
        adv[s] = 128;   // 64 k-cols * 2B per period
      }
    }
  }
  auto stagep = [&](char* dst) {
#pragma unroll
    for (int s = 0; s < 6; s++) {
      gll16(gp[s], dst + ldso[s]);
      gp[s] += adv[s];
    }
  };

  // ---- LDS read offsets ----
  int swz = (lo & 7) << 4;
  int offK[4], offVT[2];
#pragma unroll
  for (int c = 0; c < 4; c++) offK[c] = lo * 128 + ((c * 32 + hi * 16) ^ swz);
#pragma unroll
  for (int kc = 0; kc < 2; kc++)
    offVT[kc] = 16384 + lo * 128 + ((grp * 64 + kc * 32 + hi * 16) ^ swz);

  auto cvtpk = [](float a, float b) -> u32 {
    u32 r;
    asm("v_cvt_pk_bf16_f32 %0, %1, %2" : "=v"(r) : "v"(a), "v"(b));
    return r;
  };

  f32x16 oa0, oa1;  // O^T: lane holds d=(r&3)+8*(r>>2)+4*hi (+32 for oa1), q=lo
#pragma unroll
  for (int r = 0; r < 16; r++) { oa0[r] = 0.f; oa1[r] = 0.f; }
  float l_run = 0.f;
  const int iband = irow - 129;

  // ---- main loop: ping-pong halves, stage(p+1) during compute(p) ----
  stagep(sm);
  __syncthreads();
  int j0g = jstart + grp * 32;

  for (int p = 0; p < nper; p++) {
    char* half = sm + (p & 1) * 24576;
    if (p + 1 < nper) stagep(sm + ((p + 1) & 1) * 24576);
    const char* Kr = half + grp * 8192;
    const char* Ki = Kr + 4096;

    // S^T = Kr@Qr^T + Ki@Qi^T (32k x 32q)
    f32x16 s0;
#pragma unroll
    for (int r = 0; r < 16; r++) s0[r] = 0.f;
#pragma unroll
    for (int c = 0; c < 4; c++) {
      bf16x8 ar = *(const bf16x8*)(Kr + offK[c]);
      bf16x8 ai = *(const bf16x8*)(Ki + offK[c]);
      __builtin_amdgcn_s_setprio(1);
      s0 = __builtin_amdgcn_mfma_f32_32x32x16_bf16(ar, fqr[c], s0, 0, 0, 0);
      s0 = __builtin_amdgcn_mfma_f32_32x32x16_bf16(ai, fqi[c], s0, 0, 0, 0);
      __builtin_amdgcn_s_setprio(0);
    }
    // banded mask (first tiles of a block only)
    if (j0g <= i0w - 98) {
#pragma unroll
      for (int r = 0; r < 16; r++) {
        int kk = j0g + (r & 3) + ((r >> 2) << 3) + (hi << 2);
        if (kk <= iband) s0[r] = -3e38f;
      }
    }
    // P = 2^S via raw v_exp_f32; psum (mirror-lane merge REQUIRED: hi-halves per lane)
    float ps0 = 0.f, ps1 = 0.f, ps2 = 0.f, ps3 = 0.f;
#pragma unroll
    for (int r = 0; r < 16; r += 4) {
      s0[r] = fexp2(s0[r]);         ps0 += s0[r];
      s0[r + 1] = fexp2(s0[r + 1]); ps1 += s0[r + 1];
      s0[r + 2] = fexp2(s0[r + 2]); ps2 += s0[r + 2];
      s0[r + 3] = fexp2(s0[r + 3]); ps3 += s0[r + 3];
    }
    float psum = (ps0 + ps1) + (ps2 + ps3);
    psum += __shfl_xor(psum, 32);
    l_run += psum;

    // P^T B-fragments in-register (cvt_pk + permlane32_swap)
    bf16x8 pf0, pf1;
    {
      const float* pp = (const float*)&s0;
      u32 x0 = cvtpk(pp[0], pp[1]), y0 = cvtpk(pp[4], pp[5]);
      u32 x1 = cvtpk(pp[2], pp[3]), y1 = cvtpk(pp[6], pp[7]);
      u32 x2 = cvtpk(pp[8], pp[9]), y2 = cvtpk(pp[12], pp[13]);
      u32 x3 = cvtpk(pp[10], pp[11]), y3 = cvtpk(pp[14], pp[15]);
      asm("v_permlane32_swap_b32 %0, %1" : "+v"(x0), "+v"(y0));
      asm("v_permlane32_swap_b32 %0, %1" : "+v"(x1), "+v"(y1));
      asm("v_permlane32_swap_b32 %0, %1" : "+v"(x2), "+v"(y2));
      asm("v_permlane32_swap_b32 %0, %1" : "+v"(x3), "+v"(y3));
      u32x4 a; a[0] = x0; a[1] = x1; a[2] = y0; a[3] = y1;
      u32x4 b; b[0] = x2; b[1] = x3; b[2] = y2; b[3] = y3;
      pf0 = __builtin_bit_cast(bf16x8, a);
      pf1 = __builtin_bit_cast(bf16x8, b);
    }
    // O^T += V^T @ P^T  (VT rows 128B; av01/av11 = rows +32 -> +4096B)
    {
      bf16x8 av00 = *(const bf16x8*)(half + offVT[0]);
      bf16x8 av01 = *(const bf16x8*)(half + offVT[0] + 4096);
      bf16x8 av10 = *(const bf16x8*)(half + offVT[1]);
      bf16x8 av11 = *(const bf16x8*)(half + offVT[1] + 4096);
      __builtin_amdgcn_s_setprio(1);
      oa0 = __builtin_amdgcn_mfma_f32_32x32x16_bf16(av00, pf0, oa0, 0, 0, 0);
      oa1 = __builtin_amdgcn_mfma_f32_32x32x16_bf16(av01, pf0, oa1, 0, 0, 0);
      oa0 = __builtin_amdgcn_mfma_f32_32x32x16_bf16(av10, pf1, oa0, 0, 0, 0);
      oa1 = __builtin_amdgcn_mfma_f32_32x32x16_bf16(av11, pf1, oa1, 0, 0, 0);
      __builtin_amdgcn_s_setprio(0);
    }
    j0g += 64;
    __syncthreads();
  }

  // ---- exact merge (no max): O = O0+O1, l = l0+l1; grp0 writes obf ----
  int swo = (lo & 7) << 4;
  char* ob = sm + wq * 8192;  // [q=32][d=64] f32, swizzled 16B slots
  if (grp == 1) {
#pragma unroll
    for (int g2 = 0; g2 < 4; g2++) {
      f32x4 v0; f32x4 v1;
#pragma unroll
      for (int e = 0; e < 4; e++) { v0[e] = oa0[4 * g2 + e]; v1[e] = oa1[4 * g2 + e]; }
      *(f32x4*)(ob + lo * 256 + ((g2 * 32 + hi * 16) ^ swo)) = v0;
      *(f32x4*)(ob + lo * 256 + ((128 + g2 * 32 + hi * 16) ^ swo)) = v1;
    }
    if (!hi) *(float*)(sm + 16384 + wq * 128 + lo * 4) = l_run;
  }
  __syncthreads();
  if (grp == 0) {
    float l2 = *(const float*)(sm + 16384 + wq * 128 + lo * 4);
    float rl = 1.0f / (l_run + l2);
    u16* orow = obf + ((size_t)(bb * 4096 + irow) << 9) + hh * 64;
#pragma unroll
    for (int g2 = 0; g2 < 4; g2++) {
      f32x4 v0 = *(const f32x4*)(ob + lo * 256 + ((g2 * 32 + hi * 16) ^ swo));
      f32x4 v1 = *(const f32x4*)(ob + lo * 256 + ((128 + g2 * 32 + hi * 16) ^ swo));
      ushort4 o0 = make_ushort4(f2bf((oa0[4 * g2] + v0[0]) * rl),
                                f2bf((oa0[4 * g2 + 1] + v0[1]) * rl),
                                f2bf((oa0[4 * g2 + 2] + v0[2]) * rl),
                                f2bf((oa0[4 * g2 + 3] + v0[3]) * rl));
      *(ushort4*)(orow + g2 * 8 + hi * 4) = o0;
      ushort4 o1 = make_ushort4(f2bf((oa1[4 * g2] + v1[0]) * rl),
                                f2bf((oa1[4 * g2 + 1] + v1[1]) * rl),
                                f2bf((oa1[4 * g2 + 2] + v1[2]) * rl),
                                f2bf((oa1[4 * g2 + 3] + v1[3]) * rl));
      *(ushort4*)(orow + 32 + g2 * 8 + hi * 4) = o1;
    }
  }
}

// ---------------- launch ----------------
extern "C" void kernel_launch(void* const* d_in, const int* in_sizes, int n_in,
                              void* d_out, int out_size, void* d_ws, size_t ws_size,
                              hipStream_t stream) {
  (void)in_sizes; (void)n_in; (void)out_size; (void)ws_size;
  const float* q = (const float*)d_in[0];
  const float* k = (const float*)d_in[1];
  const float* v = (const float*)d_in[2];
  char* ws = (char*)d_ws;
  u16* wcat = (u16*)(ws + 0x000000);     // 3584x512 bf16
  float* bcat = (float*)(ws + 0x400000); // 3584 f32
  u16* xq  = (u16*)(ws + 0x500000);
  u16* xk  = (u16*)(ws + 0xD00000);
  u16* xv  = (u16*)(ws + 0x1500000);
  u16* qrb = (u16*)(ws + 0x1D00000);
  u16* qib = (u16*)(ws + 0x2500000);
  u16* krb = (u16*)(ws + 0x2D00000);
  u16* kib = (u16*)(ws + 0x3500000);
  u16* vtb = (u16*)(ws + 0x3D00000);
  u16* obf = xq;  // xq dead after proj; reuse for attention output
  float* out = (float*)d_out;

  cvt_x_kernel<<<2048, 256, 0, stream>>>(q, k, v, xq, xk, xv);

  CPtrs cp;
  cp.w[0] = (const float*)d_in[3];  cp.w[1] = (const float*)d_in[4];
  cp.w[2] = (const float*)d_in[7];  cp.w[3] = (const float*)d_in[8];
  cp.w[4] = (const float*)d_in[11]; cp.w[5] = (const float*)d_in[15]; cp.w[6] = (const float*)d_in[16];
  cp.b[0] = (const float*)d_in[5];  cp.b[1] = (const float*)d_in[6];
  cp.b[2] = (const float*)d_in[9];  cp.b[3] = (const float*)d_in[10];
  cp.b[4] = (const float*)d_in[13]; cp.b[5] = (const float*)d_in[17]; cp.b[6] = (const float*)d_in[18];
  cvt_wb_kernel<<<448, 256, 0, stream>>>(cp, wcat, bcat);

  proj_kernel<<<dim3(20, 64), 256, 0, stream>>>(xq, xk, xv, wcat, bcat, qrb, qib, krb, kib, vtb);
  attn_kernel<<<1024, 256, 0, stream>>>(qrb, qib, krb, kib, vtb, obf);
  oproj_kernel<<<dim3(8, 64), 256, 0, stream>>>(obf, wcat, bcat, out);
}

// Round 14
// 166.413 us; speedup vs baseline: 1.0016x; 1.0016x over previous
//
#include <hip/hip_runtime.h>

// ComplexMultiheadAttention, MI355X/gfx950.
// Pipeline: cvt(f32->bf16) -> proj GEMMs (qr,qi,kr,ki,vr^T) -> banded flash attn -> out proj.
// B=2, L=4096, E=512, H=8, D=64, W=128 (mask: j <= i-129 is -inf; NO causal/upper mask).
// Softmax in log2 domain (0.125*log2(e) folded into q proj), NO max tracking (scores O(1);
// constant max cancels in O/l; masked -3e38 underflows to 0).
// exp2 via RAW v_exp_f32 (not exp2f -> OCML precise-path bloat: ~10-15 VALU insts/call).
// Attn: QB=64, 4 waves = 2 q-waves x 2 k-groups; KB=32. 1024 blocks (heavy-first),
// 48KB LDS ping-pong -> 3 blocks/CU + backfill. Exact in-LDS merge: O=O0+O1, l=l0+l1.

typedef unsigned short u16;
typedef unsigned int u32;
typedef __attribute__((ext_vector_type(8))) short bf16x8;
typedef __attribute__((ext_vector_type(4))) float f32x4;
typedef __attribute__((ext_vector_type(16))) float f32x16;
typedef __attribute__((ext_vector_type(4))) u32 u32x4;

#define L_ 4096
#define E_ 512
#define M_ 8192  // B*L

__device__ __forceinline__ u16 f2bf(float f) {
  union { float f; u32 u; } v; v.f = f;
  return (u16)((v.u + 0x7FFFu + ((v.u >> 16) & 1u)) >> 16);  // RNE
}

__device__ __forceinline__ float fexp2(float x) {
  float r;
  asm("v_exp_f32 %0, %1" : "=v"(r) : "v"(x));  // HW 2^x: 1-ulp, underflows to 0
  return r;
}

__device__ __forceinline__ void gll16(const void* g, void* l) {
  __builtin_amdgcn_global_load_lds(
      (const __attribute__((address_space(1))) u32*)g,
      (__attribute__((address_space(3))) u32*)l, 16, 0, 0);
}

// ---------------- conversion kernels ----------------
__global__ void cvt_x_kernel(const float* __restrict__ q, const float* __restrict__ k,
                             const float* __restrict__ v,
                             u16* __restrict__ xq, u16* __restrict__ xk, u16* __restrict__ xv) {
  const int total = 3 * (M_ * E_ / 4);  // float4 units, 1<<20 per matrix
  int stride = gridDim.x * blockDim.x;
  for (int u = blockIdx.x * blockDim.x + threadIdx.x; u < total; u += stride) {
    int mat = u >> 20, e = u & ((1 << 20) - 1);
    const float4 f = ((const float4*)(mat == 0 ? q : mat == 1 ? k : v))[e];
    ushort4 o = make_ushort4(f2bf(f.x), f2bf(f.y), f2bf(f.z), f2bf(f.w));
    *(ushort4*)((mat == 0 ? xq : mat == 1 ? xk : xv) + (size_t)e * 4) = o;
  }
}

struct CPtrs { const float* w[7]; const float* b[7]; };

__global__ void cvt_wb_kernel(CPtrs p, u16* __restrict__ wcat, float* __restrict__ bcat) {
  // wcat rows: [qWr|qWi|kWr|kWi|vWr|oWr|oWi], each 512x512. bcat matching biases.
  const int total = 7 * (E_ * E_ / 4);  // 65536 float4 per matrix
  int stride = gridDim.x * blockDim.x;
  int t0 = blockIdx.x * blockDim.x + threadIdx.x;
  for (int u = t0; u < total; u += stride) {
    int wi = u >> 16, e = u & 65535;
    const float4 f = ((const float4*)p.w[wi])[e];
    ushort4 o = make_ushort4(f2bf(f.x), f2bf(f.y), f2bf(f.z), f2bf(f.w));
    *(ushort4*)(wcat + (size_t)wi * 262144 + (size_t)e * 4) = o;
  }
  for (int j = t0; j < 3584; j += stride) bcat[j] = p.b[j >> 9][j & 511];
}

// ---------------- 128x128 bf16 GEMM mainloop (C = A @ W^T), K=512, BK=32 ----------------
__device__ __forceinline__ void gemm128_main(const u16* __restrict__ A, const u16* __restrict__ Bw,
                                             int m0, int n0w, char* sm, f32x4 acc[4][4]) {
  int tid = threadIdx.x;
  int lane = tid & 63, w = tid >> 6;
  int wm = w >> 1, wn = w & 1;
#pragma unroll
  for (int a = 0; a < 4; a++)
#pragma unroll
    for (int b = 0; b < 4; b++)
#pragma unroll
      for (int j = 0; j < 4; j++) acc[a][b][j] = 0.f;

  auto stage = [&](int buf, int ks) {
    char* dst = sm + buf * 16384;
#pragma unroll
    for (int n = 0; n < 2; n++) {
      int u = n * 256 + tid;
      int row = u >> 2, c = u & 3;
      int so = (c ^ (row & 3)) * 16;  // pre-swizzled source chunk (LDS stays linear)
      int ldso = (n * 256 + w * 64) * 16;
      gll16((const char*)(A + (size_t)(m0 + row) * 512 + ks * 32) + so, dst + ldso);
      gll16((const char*)(Bw + (size_t)(n0w + row) * 512 + ks * 32) + so, dst + 8192 + ldso);
    }
  };

  stage(0, 0);
  __syncthreads();
  int cur = 0;
  for (int ks = 0; ks < 16; ks++) {
    if (ks < 15) stage(cur ^ 1, ks + 1);
    const char* as = sm + cur * 16384;
    const char* bs = as + 8192;
    bf16x8 af[4], bfr[4];
#pragma unroll
    for (int i = 0; i < 4; i++) {
      int ra = wm * 64 + i * 16 + (lane & 15);
      af[i] = *(const bf16x8*)(as + ra * 64 + (((lane >> 4) * 16) ^ ((ra & 3) << 4)));
      int rb = wn * 64 + i * 16 + (lane & 15);
      bfr[i] = *(const bf16x8*)(bs + rb * 64 + (((lane >> 4) * 16) ^ ((rb & 3) << 4)));
    }
    __builtin_amdgcn_s_setprio(1);
#pragma unroll
    for (int mt = 0; mt < 4; mt++)
#pragma unroll
      for (int nt = 0; nt < 4; nt++)
        acc[mt][nt] = __builtin_amdgcn_mfma_f32_16x16x32_bf16(af[mt], bfr[nt], acc[mt][nt], 0, 0, 0);
    __builtin_amdgcn_s_setprio(0);
    __syncthreads();
    cur ^= 1;
  }
}

// ---------------- projection kernel (q,k,v jobs) ----------------
__global__ __launch_bounds__(256) void proj_kernel(
    const u16* __restrict__ xq, const u16* __restrict__ xk, const u16* __restrict__ xv,
    const u16* __restrict__ wcat, const float* __restrict__ bcat,
    u16* __restrict__ qrb, u16* __restrict__ qib,
    u16* __restrict__ krb, u16* __restrict__ kib, u16* __restrict__ vtb) {
  __shared__ alignas(16) char sm[32768];
  int bx = blockIdx.x, by = blockIdx.y;  // bx<8: q (N=1024), bx<16: k, else v (N=512)
  const u16* A = bx < 8 ? xq : (bx < 16 ? xk : xv);
  int m0 = by * 128, n0w = bx * 128;
  f32x4 acc[4][4];
  gemm128_main(A, wcat, m0, n0w, sm, acc);

  int lane = threadIdx.x & 63, w = threadIdx.x >> 6;
  int wm = w >> 1, wn = w & 1;
  int lL = lane & 15, lH = lane >> 4;
#pragma unroll
  for (int mt = 0; mt < 4; mt++) {
#pragma unroll
    for (int nt = 0; nt < 4; nt++) {
      int n = n0w + wn * 64 + nt * 16 + lL;  // global wcat row
      float bias = bcat[n];
      int e = n & 511;
#pragma unroll
      for (int j = 0; j < 4; j++) {
        int m = m0 + wm * 64 + mt * 16 + lH * 4 + j;
        float val = acc[mt][nt][j] + bias;
        int bb = m >> 12, ll = m & 4095;
        if (bx < 16) {
          if (bx < 8) val *= 0.18033688011112042f;  // 1/sqrt(D) * log2(e) folded into q
          u16* dst = (bx < 8) ? ((n & 512) ? qib : qrb) : ((n & 512) ? kib : krb);
          dst[((size_t)((bb * 8 + (e >> 6)) * 4096 + ll) << 6) + (e & 63)] = f2bf(val);
        } else {
          // vr stored transposed: VT[bh][d][l]
          vtb[((size_t)((bb * 8 + (e >> 6)) * 64 + (e & 63)) << 12) + ll] = f2bf(val);
        }
      }
    }
  }
}

// ---------------- output projection kernel ----------------
__global__ __launch_bounds__(256) void oproj_kernel(
    const u16* __restrict__ obf, const u16* __restrict__ wcat, const float* __restrict__ bcat,
    float* __restrict__ out) {
  __shared__ alignas(16) char sm[32768];
  int bx = blockIdx.x, by = blockIdx.y;
  int m0 = by * 128, n0w = 2560 + bx * 128;
  f32x4 acc[4][4];
  gemm128_main(obf, wcat, m0, n0w, sm, acc);

  int lane = threadIdx.x & 63, w = threadIdx.x >> 6;
  int wm = w >> 1, wn = w & 1;
  int lL = lane & 15, lH = lane >> 4;
#pragma unroll
  for (int mt = 0; mt < 4; mt++) {
#pragma unroll
    for (int nt = 0; nt < 4; nt++) {
      int n = n0w + wn * 64 + nt * 16 + lL;
      float bias = bcat[n];
      int nn = n - 2560;
      // out_r at [0, 4194304), out_i at [4194304, 8388608)  (B*L*E = 4194304 each)
      float* dst = out + ((nn & 512) ? 4194304 : 0) + (nn & 511);
#pragma unroll
      for (int j = 0; j < 4; j++) {
        int m = m0 + wm * 64 + mt * 16 + lH * 4 + j;
        dst[(size_t)m * 512] = acc[mt][nt][j] + bias;
      }
    }
  }
}

// ---------------- banded flash attention (QB=64, 4 waves, 2 k-groups, backfilled) -----
// Waves: wq = w&1 (q-wave, 32 rows each), grp = w>>1 (k-group, tiles t%2==grp, KB=32).
// Swapped QK^T: S^T = mfma(K, Q); layout col=lane&31 (=q), row=(r&3)+8*(r>>2)+4*hi (=k).
// LDS: 2 x 24KB ping-pong halves. Half layout: KrA@0 KiA@4K KrB@8K KiB@12K (each 32x128B,
// XOR-swizzled rows) | VT@16K = [64d][64k] rows of 128B (both tiles' k), same swizzle.
// 24 chunks x 1KB (8 rows x 128B); thread stages 6 chunks/period via gll16.
__global__ __launch_bounds__(256, 3) void attn_kernel(
    const u16* __restrict__ qrb, const u16* __restrict__ qib,
    const u16* __restrict__ krb, const u16* __restrict__ kib,
    const u16* __restrict__ vtb, u16* __restrict__ obf) {
  __shared__ alignas(16) char sm[49152];  // 2 x 24KB; epilogue reuses ~17KB
  int bid = blockIdx.x;
  int bh = bid & 15;          // bh pins to XCD (bid%8==bh%8)
  int qt = bid >> 4;          // 0..63, ascending = heavy-first (backfill-friendly)
  int bb = bh >> 3, hh = bh & 7;
  int i0 = qt << 6;
  int tid = threadIdx.x;
  int lane = tid & 63, w = tid >> 6;    // w 0..3
  int grp = w >> 1, wq = w & 1;
  int lo = lane & 31, hi = lane >> 5;
  int i0w = i0 + wq * 32;
  int irow = i0w + lo;

  int jstart = (i0 >= 128) ? (i0 - 128) : 0;
  int ntiles = (4096 - jstart) >> 5;  // KB=32; always even
  int nper = ntiles >> 1;

  // ---- Q fragments (B-operand): lane holds Q[q=lo][d = c*16 + hi*8 + i] ----
  bf16x8 fqr[4], fqi[4];
  {
    const u16* qp = qrb + ((size_t)(bh * 4096 + irow) << 6) + hi * 8;
    const u16* qip = qib + ((size_t)(bh * 4096 + irow) << 6) + hi * 8;
#pragma unroll
    for (int c = 0; c < 4; c++) {
      fqr[c] = *(const bf16x8*)(qp + c * 16);
      fqi[c] = *(const bf16x8*)(qip + c * 16);
    }
  }

  // ---- per-thread staging constants: 6 chunks (1KB = 8 rows x 128B) per period ----
  // cc = 6w+s: 0-3 KrA, 4-7 KiA, 8-11 KrB, 12-15 KiB, 16-23 VT[64d][64k-per-period].
  const char* gp[6];
  int adv[6], ldso[6];
  {
    const char* krbB = (const char*)krb + ((size_t)(bh * 4096 + jstart) << 7);
    const char* kibB = (const char*)kib + ((size_t)(bh * 4096 + jstart) << 7);
    const char* vtbB = (const char*)vtb + ((size_t)(bh * 64) << 13) + ((size_t)jstart << 1);
#pragma unroll
    for (int s = 0; s < 6; s++) {
      int cc = 6 * w + s;
      ldso[s] = cc << 10;
      if (cc < 16) {  // K chunks: tile tI=cc>>3, kind=(cc>>2)&1 (Kr/Ki), rows 32 x 128B
        int tI = cc >> 3;
        int kind = (cc >> 2) & 1;
        int r = (cc & 3) * 8 + (lane >> 3);
        int so = ((lane & 7) ^ (r & 7)) << 4;
        gp[s] = (kind ? kibB : krbB) + (size_t)(tI * 32 + r) * 128 + so;
        adv[s] = 8192;  // 64 k-rows per period
      } else {        // VT chunks: rows d, 128B = 64 k (both tiles)
        int dr = (cc - 16) * 8 + (lane >> 3);
        int so = ((lane & 7) ^ (dr & 7)) << 4;
        gp[s] = vtbB + (size_t)dr * 8192 + so;
        adv[s] = 128;   // 64 k-cols * 2B per period
      }
    }
  }
  auto stagep = [&](char* dst) {
#pragma unroll
    for (int s = 0; s < 6; s++) {
      gll16(gp[s], dst + ldso[s]);
      gp[s] += adv[s];
    }
  };

  // ---- LDS read offsets ----
  int swz = (lo & 7) << 4;
  int offK[4], offVT[2];
#pragma unroll
  for (int c = 0; c < 4; c++) offK[c] = lo * 128 + ((c * 32 + hi * 16) ^ swz);
#pragma unroll
  for (int kc = 0; kc < 2; kc++)
    offVT[kc] = 16384 + lo * 128 + ((grp * 64 + kc * 32 + hi * 16) ^ swz);

  auto cvtpk = [](float a, float b) -> u32 {
    u32 r;
    asm("v_cvt_pk_bf16_f32 %0, %1, %2" : "=v"(r) : "v"(a), "v"(b));
    return r;
  };

  f32x16 oa0, oa1;  // O^T: lane holds d=(r&3)+8*(r>>2)+4*hi (+32 for oa1), q=lo
#pragma unroll
  for (int r = 0; r < 16; r++) { oa0[r] = 0.f; oa1[r] = 0.f; }
  float l_run = 0.f;
  const int iband = irow - 129;

  // ---- main loop: ping-pong halves, stage(p+1) during compute(p) ----
  stagep(sm);
  __syncthreads();
  int j0g = jstart + grp * 32;

  for (int p = 0; p < nper; p++) {
    char* half = sm + (p & 1) * 24576;
    if (p + 1 < nper) stagep(sm + ((p + 1) & 1) * 24576);
    const char* Kr = half + grp * 8192;
    const char* Ki = Kr + 4096;

    // S^T = Kr@Qr^T + Ki@Qi^T (32k x 32q)
    f32x16 s0;
#pragma unroll
    for (int r = 0; r < 16; r++) s0[r] = 0.f;
#pragma unroll
    for (int c = 0; c < 4; c++) {
      bf16x8 ar = *(const bf16x8*)(Kr + offK[c]);
      bf16x8 ai = *(const bf16x8*)(Ki + offK[c]);
      __builtin_amdgcn_s_setprio(1);
      s0 = __builtin_amdgcn_mfma_f32_32x32x16_bf16(ar, fqr[c], s0, 0, 0, 0);
      s0 = __builtin_amdgcn_mfma_f32_32x32x16_bf16(ai, fqi[c], s0, 0, 0, 0);
      __builtin_amdgcn_s_setprio(0);
    }
    // banded mask (first tiles of a block only)
    if (j0g <= i0w - 98) {
#pragma unroll
      for (int r = 0; r < 16; r++) {
        int kk = j0g + (r & 3) + ((r >> 2) << 3) + (hi << 2);
        if (kk <= iband) s0[r] = -3e38f;
      }
    }
    // P = 2^S via raw v_exp_f32; psum (mirror-lane merge REQUIRED: hi-halves per lane)
    float ps0 = 0.f, ps1 = 0.f, ps2 = 0.f, ps3 = 0.f;
#pragma unroll
    for (int r = 0; r < 16; r += 4) {
      s0[r] = fexp2(s0[r]);         ps0 += s0[r];
      s0[r + 1] = fexp2(s0[r + 1]); ps1 += s0[r + 1];
      s0[r + 2] = fexp2(s0[r + 2]); ps2 += s0[r + 2];
      s0[r + 3] = fexp2(s0[r + 3]); ps3 += s0[r + 3];
    }
    float psum = (ps0 + ps1) + (ps2 + ps3);
    psum += __shfl_xor(psum, 32);
    l_run += psum;

    // P^T B-fragments in-register (cvt_pk + permlane32_swap)
    bf16x8 pf0, pf1;
    {
      const float* pp = (const float*)&s0;
      u32 x0 = cvtpk(pp[0], pp[1]), y0 = cvtpk(pp[4], pp[5]);
      u32 x1 = cvtpk(pp[2], pp[3]), y1 = cvtpk(pp[6], pp[7]);
      u32 x2 = cvtpk(pp[8], pp[9]), y2 = cvtpk(pp[12], pp[13]);
      u32 x3 = cvtpk(pp[10], pp[11]), y3 = cvtpk(pp[14], pp[15]);
      asm("v_permlane32_swap_b32 %0, %1" : "+v"(x0), "+v"(y0));
      asm("v_permlane32_swap_b32 %0, %1" : "+v"(x1), "+v"(y1));
      asm("v_permlane32_swap_b32 %0, %1" : "+v"(x2), "+v"(y2));
      asm("v_permlane32_swap_b32 %0, %1" : "+v"(x3), "+v"(y3));
      u32x4 a; a[0] = x0; a[1] = x1; a[2] = y0; a[3] = y1;
      u32x4 b; b[0] = x2; b[1] = x3; b[2] = y2; b[3] = y3;
      pf0 = __builtin_bit_cast(bf16x8, a);
      pf1 = __builtin_bit_cast(bf16x8, b);
    }
    // O^T += V^T @ P^T  (VT rows 128B; av01/av11 = rows +32 -> +4096B)
    {
      bf16x8 av00 = *(const bf16x8*)(half + offVT[0]);
      bf16x8 av01 = *(const bf16x8*)(half + offVT[0] + 4096);
      bf16x8 av10 = *(const bf16x8*)(half + offVT[1]);
      bf16x8 av11 = *(const bf16x8*)(half + offVT[1] + 4096);
      __builtin_amdgcn_s_setprio(1);
      oa0 = __builtin_amdgcn_mfma_f32_32x32x16_bf16(av00, pf0, oa0, 0, 0, 0);
      oa1 = __builtin_amdgcn_mfma_f32_32x32x16_bf16(av01, pf0, oa1, 0, 0, 0);
      oa0 = __builtin_amdgcn_mfma_f32_32x32x16_bf16(av10, pf1, oa0, 0, 0, 0);
      oa1 = __builtin_amdgcn_mfma_f32_32x32x16_bf16(av11, pf1, oa1, 0, 0, 0);
      __builtin_amdgcn_s_setprio(0);
    }
    j0g += 64;
    __syncthreads();
  }

  // ---- exact merge (no max): O = O0+O1, l = l0+l1; grp0 writes obf ----
  int swo = (lo & 7) << 4;
  char* ob = sm + wq * 8192;  // [q=32][d=64] f32, swizzled 16B slots
  if (grp == 1) {
#pragma unroll
    for (int g2 = 0; g2 < 4; g2++) {
      f32x4 v0; f32x4 v1;
#pragma unroll
      for (int e = 0; e < 4; e++) { v0[e] = oa0[4 * g2 + e]; v1[e] = oa1[4 * g2 + e]; }
      *(f32x4*)(ob + lo * 256 + ((g2 * 32 + hi * 16) ^ swo)) = v0;
      *(f32x4*)(ob + lo * 256 + ((128 + g2 * 32 + hi * 16) ^ swo)) = v1;
    }
    if (!hi) *(float*)(sm + 16384 + wq * 128 + lo * 4) = l_run;
  }
  __syncthreads();
  if (grp == 0) {
    float l2 = *(const float*)(sm + 16384 + wq * 128 + lo * 4);
    float rl = 1.0f / (l_run + l2);
    u16* orow = obf + ((size_t)(bb * 4096 + irow) << 9) + hh * 64;
#pragma unroll
    for (int g2 = 0; g2 < 4; g2++) {
      f32x4 v0 = *(const f32x4*)(ob + lo * 256 + ((g2 * 32 + hi * 16) ^ swo));
      f32x4 v1 = *(const f32x4*)(ob + lo * 256 + ((128 + g2 * 32 + hi * 16) ^ swo));
      ushort4 o0 = make_ushort4(f2bf((oa0[4 * g2] + v0[0]) * rl),
                                f2bf((oa0[4 * g2 + 1] + v0[1]) * rl),
                                f2bf((oa0[4 * g2 + 2] + v0[2]) * rl),
                                f2bf((oa0[4 * g2 + 3] + v0[3]) * rl));
      *(ushort4*)(orow + g2 * 8 + hi * 4) = o0;
      ushort4 o1 = make_ushort4(f2bf((oa1[4 * g2] + v1[0]) * rl),
                                f2bf((oa1[4 * g2 + 1] + v1[1]) * rl),
                                f2bf((oa1[4 * g2 + 2] + v1[2]) * rl),
                                f2bf((oa1[4 * g2 + 3] + v1[3]) * rl));
      *(ushort4*)(orow + 32 + g2 * 8 + hi * 4) = o1;
    }
  }
}

// ---------------- launch ----------------
extern "C" void kernel_launch(void* const* d_in, const int* in_sizes, int n_in,
                              void* d_out, int out_size, void* d_ws, size_t ws_size,
                              hipStream_t stream) {
  (void)in_sizes; (void)n_in; (void)out_size; (void)ws_size;
  const float* q = (const float*)d_in[0];
  const float* k = (const float*)d_in[1];
  const float* v = (const float*)d_in[2];
  char* ws = (char*)d_ws;
  u16* wcat = (u16*)(ws + 0x000000);     // 3584x512 bf16
  float* bcat = (float*)(ws + 0x400000); // 3584 f32
  u16* xq  = (u16*)(ws + 0x500000);
  u16* xk  = (u16*)(ws + 0xD00000);
  u16* xv  = (u16*)(ws + 0x1500000);
  u16* qrb = (u16*)(ws + 0x1D00000);
  u16* qib = (u16*)(ws + 0x2500000);
  u16* krb = (u16*)(ws + 0x2D00000);
  u16* kib = (u16*)(ws + 0x3500000);
  u16* vtb = (u16*)(ws + 0x3D00000);
  u16* obf = xq;  // xq dead after proj; reuse for attention output
  float* out = (float*)d_out;

  cvt_x_kernel<<<2048, 256, 0, stream>>>(q, k, v, xq, xk, xv);

  CPtrs cp;
  cp.w[0] = (const float*)d_in[3];  cp.w[1] = (const float*)d_in[4];
  cp.w[2] = (const float*)d_in[7];  cp.w[3] = (const float*)d_in[8];
  cp.w[4] = (const float*)d_in[11]; cp.w[5] = (const float*)d_in[15]; cp.w[6] = (const float*)d_in[16];
  cp.b[0] = (const float*)d_in[5];  cp.b[1] = (const float*)d_in[6];
  cp.b[2] = (const float*)d_in[9];  cp.b[3] = (const float*)d_in[10];
  cp.b[4] = (const float*)d_in[13]; cp.b[5] = (const float*)d_in[17]; cp.b[6] = (const float*)d_in[18];
  cvt_wb_kernel<<<448, 256, 0, stream>>>(cp, wcat, bcat);

  proj_kernel<<<dim3(20, 64), 256, 0, stream>>>(xq, xk, xv, wcat, bcat, qrb, qib, krb, kib, vtb);
  attn_kernel<<<1024, 256, 0, stream>>>(qrb, qib, krb, kib, vtb, obf);
  oproj_kernel<<<dim3(8, 64), 256, 0, stream>>>(obf, wcat, bcat, out);
}